// Round 20
// baseline (65.775 us; speedup 1.0000x reference)
//
#include <hip/hip_runtime.h>

typedef float f32x4 __attribute__((ext_vector_type(4)));
typedef __bf16 bf16x8 __attribute__((ext_vector_type(8)));
typedef unsigned short u16x8 __attribute__((ext_vector_type(8)));

__device__ __forceinline__ unsigned short f2bf(float f) {
  union { float f; unsigned u; } v; v.f = f;
  unsigned r = v.u + 0x7FFFu + ((v.u >> 16) & 1u);
  return (unsigned short)(r >> 16);
}

__device__ __forceinline__ float min3f(float a, float b, float c) {
  return fminf(fminf(a, b), c);
}
__device__ __forceinline__ float max3f(float a, float b, float c) {
  return fmaxf(fmaxf(a, b), c);
}
__device__ __forceinline__ float med3f(float a, float b, float c) {
  return __builtin_amdgcn_fmed3f(a, b, c);
}

// async global->LDS, 16B per lane, LDS dest = wave-uniform base + lane*16
__device__ __forceinline__ void gload_lds16(const void* g, void* l) {
  __builtin_amdgcn_global_load_lds(
      (const __attribute__((address_space(1))) void*)g,
      (__attribute__((address_space(3))) void*)l, 16, 0, 0);
}

// conv_w fp32 [256][256] -> bf16 in MFMA-fragment-linear order:
// wbf[((ks*16 + ob)*64 + lane)*8 + j] = bf16(W[ob*16 + (lane&15)][ks*32 + (lane>>4)*8 + j])
__global__ void wconv_k(const float* __restrict__ w, unsigned short* __restrict__ wbf) {
  int idx  = blockIdx.x * 256 + threadIdx.x;   // 0..8191
  int lane = idx & 63;
  int ob   = (idx >> 6) & 15;
  int ks   = idx >> 10;                        // 0..7
  int o = (ob << 4) + (lane & 15);
  int c = (ks << 5) + ((lane >> 4) << 3);
  const float* src = w + (o << 8) + c;
  f32x4 v0 = *(const f32x4*)src;
  f32x4 v1 = *(const f32x4*)(src + 4);
  u16x8 ov;
  ov[0] = f2bf(v0[0]); ov[1] = f2bf(v0[1]); ov[2] = f2bf(v0[2]); ov[3] = f2bf(v0[3]);
  ov[4] = f2bf(v1[0]); ov[5] = f2bf(v1[1]); ov[6] = f2bf(v1[2]); ov[7] = f2bf(v1[3]);
  *(u16x8*)(wbf + (idx << 3)) = ov;
}

// One block = (batch, row-pair): 128 px x 256 oc, 256 threads.
// SUPERSTEP (BK=64): two K-slices (a=2j in Xs[0]/Bt[0], b=2j+1 in
// Xs[1]/Bt[1]) share one barrier pair -> 4 supersteps, 8 barriers, but
// HALF the stage->consume serialization slots of R19 and 2x the stage
// latency cover (stage pair is in flight across a 64-MFMA phase).
// Race-freedom (plain __syncthreads only): stage writes Xs[*] strictly
// after the barrier that retires all readers of the previous slices;
// Bt written pre-barrier, read post-barrier; next superstep's Bt writes
// are after the barrier that retires this superstep's pa reads.
__launch_bounds__(256, 2)
__global__ void fused_k(const float* __restrict__ x,
                        const unsigned short* __restrict__ wbf,
                        const float* __restrict__ bias,
                        float* __restrict__ out) {
  __shared__ float Xs[2][128][64];          // 64 KB: [slice parity][ci*4+dr][px-blk swz]
  __shared__ unsigned short Bt[2][128][32]; // 16 KB: [slice parity][px'][c swz]

  const int t   = threadIdx.x;
  const int blk = blockIdx.x;
  const int swz = ((blk & 7) << 7) | (blk >> 3);   // XCD-bijective (1024 = 8*128)
  const int b   = swz >> 5;
  const int r0  = (swz & 31) << 1;         // even row, rows r0 and r0+1
  const int lane = t & 63;
  const int w    = t >> 6;       // wave 0..3
  const int g    = lane >> 4;    // lane group 0..3
  const int l15  = lane & 15;

  // median task: channel ci = t>>3 (0..31), strip s = t&7 (8 px, both rows)
  const int ci  = t >> 3;
  const int s   = t & 7;
  const int px0 = s << 3;
  const int cw  = ci ^ ((s & 3) << 3);     // Bt bank-deconflict swizzle
  const bool hasL = (s > 0), hasR = (s < 7);
  const bool zTop = (r0 == 0), zBot = (r0 == 62);

  const float* xb = x + ((size_t)b << 20);   // b * 256*64*64

  float bn[4];
  #pragma unroll
  for (int n = 0; n < 4; ++n) bn[n] = bias[(w << 6) + (n << 4) + l15];

  // staging: issue p stages channel cp=8w+p, rows dr=lane>>4 (4 rows = 1 KB)
  unsigned soff[8];
  #pragma unroll
  for (int p = 0; p < 8; ++p) {
    int cp = (w << 3) + p;
    int gr = r0 + (lane >> 4) - 1;
    gr = gr < 0 ? 0 : (gr > 63 ? 63 : gr);   // clamp; zeroed in VALU at median
    int bG = (lane & 15) ^ p;                // pre-swizzle px-block by cp&7==p
    soff[p] = ((unsigned)cp << 14) + ((unsigned)gr << 8) + ((unsigned)bG << 4);
  }

  auto stage = [&](int step, int buf) {
    const unsigned kso = (unsigned)step << 19;   // step * 32ch * 16KB
    #pragma unroll
    for (int p = 0; p < 8; ++p)
      gload_lds16((const char*)xb + (soff[p] + kso), &Xs[buf][(w << 5) + (p << 2)][0]);
  };

  f32x4 acc[8][4];
  #pragma unroll
  for (int m = 0; m < 8; ++m)
    #pragma unroll
    for (int n = 0; n < 4; ++n)
      acc[m][n] = (f32x4){0.f, 0.f, 0.f, 0.f};

  const int ri0 = ci << 2;
  const int sig = ci & 7;
  const int bA  = ((s << 1)) ^ sig;
  const int bB  = ((s << 1) | 1) ^ sig;

  // median + fold for slice ks (Xs[cur] -> Bt[cur])
  auto medianSlice = [&](int cur, int ks) {
    f32x4 va[4], vb[4];
    #pragma unroll
    for (int dr = 0; dr < 4; ++dr) {
      const float* rp = &Xs[cur][ri0 + dr][0];
      va[dr] = *(const f32x4*)(rp + (bA << 2));
      vb[dr] = *(const f32x4*)(rp + (bB << 2));
    }
    float le[4], re[4];
    #pragma unroll
    for (int dr = 0; dr < 4; ++dr) {
      le[dr] = __shfl_up(vb[dr][3], 1);
      re[dr] = __shfl_down(va[dr][0], 1);
    }

    // residual fold: at slice ks = 2w+h, staged channels ARE wave w's oc
    // for n in {2h, 2h+1}; rows r0,r0+1 = dr 1,2
    if ((ks >> 1) == w) {
      const int h = ks & 1;
      #pragma unroll
      for (int nn = 0; nn < 2; ++nn) {
        const int n  = (h << 1) + nn;
        const int cx = (nn << 4) + l15;
        const int sx = cx & 7;
        const int rb = cx << 2;
        #pragma unroll
        for (int m = 0; m < 8; ++m) {
          const int bL = ((((m & 3) << 2) + g) ^ sx) << 2;
          const f32x4 xv = *(const f32x4*)&Xs[cur][rb + 1 + (m >> 2)][bL];
          acc[m][n] += xv;
        }
      }
    }

    // strip A (row r0): staged rows 0,1,2
    {
      float R0[10], R1[10], R2[10];
      R0[0] = hasL ? le[0] : 0.f; R1[0] = hasL ? le[1] : 0.f; R2[0] = hasL ? le[2] : 0.f;
      R0[9] = hasR ? re[0] : 0.f; R1[9] = hasR ? re[1] : 0.f; R2[9] = hasR ? re[2] : 0.f;
      #pragma unroll
      for (int j = 0; j < 4; ++j) {
        R0[1 + j] = va[0][j]; R0[5 + j] = vb[0][j];
        R1[1 + j] = va[1][j]; R1[5 + j] = vb[1][j];
        R2[1 + j] = va[2][j]; R2[5 + j] = vb[2][j];
      }
      if (zTop) {
        #pragma unroll
        for (int j = 0; j < 10; ++j) R0[j] = 0.f;
      }
      float mn[10], md[10], mx[10];
      #pragma unroll
      for (int j = 0; j < 10; ++j) {
        mn[j] = min3f(R0[j], R1[j], R2[j]);
        md[j] = med3f(R0[j], R1[j], R2[j]);
        mx[j] = max3f(R0[j], R1[j], R2[j]);
      }
      #pragma unroll
      for (int i = 0; i < 8; ++i) {
        float t0 = max3f(mn[i], mn[i+1], mn[i+2]);
        float t1 = med3f(md[i], md[i+1], md[i+2]);
        float t2 = min3f(mx[i], mx[i+1], mx[i+2]);
        Bt[cur][px0 + i][cw] = f2bf(med3f(t0, t1, t2));
      }
    }
    // strip B (row r0+1): staged rows 1,2,3
    {
      float R0[10], R1[10], R2[10];
      R0[0] = hasL ? le[1] : 0.f; R1[0] = hasL ? le[2] : 0.f; R2[0] = hasL ? le[3] : 0.f;
      R0[9] = hasR ? re[1] : 0.f; R1[9] = hasR ? re[2] : 0.f; R2[9] = hasR ? re[3] : 0.f;
      #pragma unroll
      for (int j = 0; j < 4; ++j) {
        R0[1 + j] = va[1][j]; R0[5 + j] = vb[1][j];
        R1[1 + j] = va[2][j]; R1[5 + j] = vb[2][j];
        R2[1 + j] = va[3][j]; R2[5 + j] = vb[3][j];
      }
      if (zBot) {
        #pragma unroll
        for (int j = 0; j < 10; ++j) R2[j] = 0.f;
      }
      float mn[10], md[10], mx[10];
      #pragma unroll
      for (int j = 0; j < 10; ++j) {
        mn[j] = min3f(R0[j], R1[j], R2[j]);
        md[j] = med3f(R0[j], R1[j], R2[j]);
        mx[j] = max3f(R0[j], R1[j], R2[j]);
      }
      #pragma unroll
      for (int i = 0; i < 8; ++i) {
        float t0 = max3f(mn[i], mn[i+1], mn[i+2]);
        float t1 = med3f(md[i], md[i+1], md[i+2]);
        float t2 = min3f(mx[i], mx[i+1], mx[i+2]);
        Bt[cur][64 + px0 + i][cw] = f2bf(med3f(t0, t1, t2));
      }
    }
  };

  auto loadWf = [&](int ks, bf16x8* wf) {
    #pragma unroll
    for (int n = 0; n < 4; ++n) {
      const int fidx = (((ks << 4) + (w << 2) + n) << 6) + lane;
      wf[n] = __builtin_bit_cast(bf16x8, *(const u16x8*)(wbf + ((size_t)fidx << 3)));
    }
  };

  auto mfmaSlice = [&](int cur, const bf16x8* wf) {
    bf16x8 pa[8];
    #pragma unroll
    for (int m = 0; m < 8; ++m) {
      const int px = (m << 4) + l15;
      const int gc = (g ^ ((px >> 3) & 3)) << 3;
      pa[m] = __builtin_bit_cast(bf16x8, *(const u16x8*)&Bt[cur][px][gc]);
    }
    #pragma unroll
    for (int m = 0; m < 8; ++m)
      #pragma unroll
      for (int n = 0; n < 4; ++n)
        acc[m][n] = __builtin_amdgcn_mfma_f32_16x16x32_bf16(pa[m], wf[n], acc[m][n], 0, 0, 0);
  };

  // prologue: both slices of superstep 0
  stage(0, 0);
  stage(1, 1);
  __syncthreads();

  #pragma unroll
  for (int j = 0; j < 4; ++j) {
    const int a  = j << 1;
    const int bb = a + 1;

    // medians + folds for both slices (reads Xs[0], Xs[1])
    bf16x8 wfa[4];
    loadWf(a, wfa);                 // L2-hot, consumed post-barrier
    medianSlice(0, a);
    medianSlice(1, bb);

    __syncthreads();                // Bt[0],Bt[1] published; all Xs reads drained

    // stage next superstep's slices: in flight across the 64-MFMA phase
    if (j < 3) { stage(a + 2, 0); stage(bb + 2, 1); }

    mfmaSlice(0, wfa);
    bf16x8 wfb[4];
    loadWf(bb, wfb);                // hidden under MFMA(a)
    mfmaSlice(1, wfb);

    if (j < 3) __syncthreads();     // stages drained; Bt consumed by all
  }

  // --- epilogue (write-only): px' = (m&3)*16+g*4+q, row r0+(m>>2) ---
  #pragma unroll
  for (int m = 0; m < 8; ++m) {
    #pragma unroll
    for (int n = 0; n < 4; ++n) {
      const int o = (w << 6) + (n << 4) + l15;
      const size_t idx = ((((size_t)b << 8) + (size_t)o) << 12)
                       + ((size_t)(r0 + (m >> 2)) << 6)
                       + (size_t)(((m & 3) << 4) + (g << 2));
      f32x4 res;
      #pragma unroll
      for (int q = 0; q < 4; ++q) res[q] = acc[m][n][q] + bn[n];
      *(f32x4*)(out + idx) = res;
    }
  }
}

extern "C" void kernel_launch(void* const* d_in, const int* in_sizes, int n_in,
                              void* d_out, int out_size, void* d_ws, size_t ws_size,
                              hipStream_t stream) {
  const float* x  = (const float*)d_in[0];
  const float* cw = (const float*)d_in[1];
  const float* cb = (const float*)d_in[2];
  float* out = (float*)d_out;
  unsigned short* wbf = (unsigned short*)d_ws;   // 128 KB fragment-linear W

  hipLaunchKernelGGL(wconv_k, dim3(32), dim3(256), 0, stream, cw, wbf);
  hipLaunchKernelGGL(fused_k, dim3(1024), dim3(256), 0, stream, x, wbf, cb, out);
}